// Round 1
// baseline (271.589 us; speedup 1.0000x reference)
//
#include <hip/hip_runtime.h>

#define DIM    512
#define KCODES 8192
#define NROWS  16384
#define NEG_INF -3.402823466e38f
#define MARGIN 1.0f            // score = dot - e_sq/2 scale; bf16 err std ~0.07
#define CPR 128                // cand slots per row: 32 col-tiles * 2 wm * 2

typedef unsigned short ushort_t;
typedef unsigned int uint_t;
typedef __attribute__((ext_vector_type(8))) short v8s;
typedef __attribute__((ext_vector_type(4))) float v4f;

__device__ inline ushort_t f32_to_bf16_rne(float f) {
    uint_t u = __float_as_uint(f);
    uint_t r = u + 0x7fffu + ((u >> 16) & 1u);
    return (ushort_t)(r >> 16);
}

__device__ inline int4 cvt8hi(float4 a, float4 b) {
    ushort_t h[8] = { f32_to_bf16_rne(a.x), f32_to_bf16_rne(a.y),
                      f32_to_bf16_rne(a.z), f32_to_bf16_rne(a.w),
                      f32_to_bf16_rne(b.x), f32_to_bf16_rne(b.y),
                      f32_to_bf16_rne(b.z), f32_to_bf16_rne(b.w) };
    int4 p;
    p.x = (int)((uint_t)h[0] | ((uint_t)h[1] << 16));
    p.y = (int)((uint_t)h[2] | ((uint_t)h[3] << 16));
    p.z = (int)((uint_t)h[4] | ((uint_t)h[5] << 16));
    p.w = (int)((uint_t)h[6] | ((uint_t)h[7] << 16));
    return p;
}

__device__ inline void dma16(const void* g, void* l) {
    __builtin_amdgcn_global_load_lds(
        (const __attribute__((address_space(1))) unsigned int*)g,
        (__attribute__((address_space(3))) unsigned int*)l, 16, 0, 0);
}

// --------- kernel 0: bf16 convert + norms + k-major TRANSPOSE ---------------
// e_t[sq][8192], x_t[sq][16384] as int4 (8 bf16 per (k-chunk sq, row)).
// LDS transpose, pad 65 + col swizzle (sq + 2r) & 63: both phases
// conflict-free (read-phase lane coefficient 67 ≡ 3 mod 8, odd).
__global__ __launch_bounds__(256) void convert_kernel(
    const float* __restrict__ x, const float* __restrict__ embed,
    int4* __restrict__ e_t, int4* __restrict__ x_t,
    float* __restrict__ e_sq, float* __restrict__ esqh,
    float* __restrict__ f_sq)
{
    __shared__ int4 buf[64][65];   // 66.6 KB

    const int w = threadIdx.x >> 6;
    const int lane = threadIdx.x & 63;
    const bool isE = blockIdx.x < (KCODES / 64);
    const int rows0 = isE ? blockIdx.x * 64 : (blockIdx.x - KCODES / 64) * 64;
    const float* src_base = isE ? embed : x;

    #pragma unroll
    for (int rr = 0; rr < 16; ++rr) {
        int r_local = w * 16 + rr;
        const float* src = src_base + (size_t)(rows0 + r_local) * DIM + lane * 8;
        float4 a = *(const float4*)src;
        float4 b = *(const float4*)(src + 4);
        buf[r_local][(lane + 2 * r_local) & 63] = cvt8hi(a, b);   // sq = lane
        float s = a.x*a.x + a.y*a.y + a.z*a.z + a.w*a.w
                + b.x*b.x + b.y*b.y + b.z*b.z + b.w*b.w;
        #pragma unroll
        for (int off = 32; off >= 1; off >>= 1) s += __shfl_down(s, off, 64);
        if (lane == 0) {
            int r = rows0 + r_local;
            if (isE) { e_sq[r] = s; esqh[r] = -0.5f * s; }
            else     { f_sq[r] = s; }
        }
    }
    __syncthreads();

    #pragma unroll
    for (int i = 0; i < 16; ++i) {
        int sq = w * 16 + i;
        int4 v = buf[lane][(sq + 2 * lane) & 63];
        if (isE) e_t[(size_t)sq * KCODES + rows0 + lane] = v;
        else     x_t[(size_t)sq * NROWS  + rows0 + lane] = v;
    }
}

// --------- kernel 1: bf16 MFMA screen — 8-phase counted-vmcnt schedule ------
// Grid: 2048 blocks = 64 row-tiles x 32 code-cols (XCD-swizzled). 1 block/CU.
// Block tile: 256 codes x 256 rows x K=512; wave tile 128x64 (acc 8x4x4 =
// 128 regs). 8 slabs of 64-k, dbuf LDS (128 KB). Each slab = 4 phases
// (ks {0,1} x mi-halves, 16 MFMA each; bh reused across mi-halves so LDS
// read traffic is unchanged). Prefetch of slab S+1 spread 2 dma16/phase;
// half-slab sync via s_waitcnt vmcnt(4) + raw s_barrier — 4 loads stay in
// flight across every barrier (drain to 0 only at the last slab). setprio(1)
// wraps each MFMA cluster. (T3+T4+T5 of the 256^2 8-phase template; LDS
// layout already conflict-free so no swizzle needed.)
__global__ __launch_bounds__(512, 2) void screen_kernel(
    const int4* __restrict__ e_t, const int4* __restrict__ x_t,
    const float* __restrict__ esqh,
    float* __restrict__ cand_s, int* __restrict__ cand_i)
{
    __shared__ __align__(16) short EH[2][8][256][8];   // 64 KB
    __shared__ __align__(16) short XH[2][8][256][8];   // 64 KB

    const int t = threadIdx.x;
    const int w = t >> 6;          // 0..7
    const int lane = t & 63;
    const int quad = lane >> 4;
    const int l15 = lane & 15;
    const int wm = w & 1;          // code half (128)
    const int wn = w >> 1;         // row quarter (64)

    const int n = blockIdx.x;
    const int xcd = n & 7;
    const int j = n >> 3;
    const int rt = xcd * 8 + (j & 7);
    const int ct = j >> 3;
    const int row0 = rt * 256;
    const int cbase = ct * 256;

    // DMA bases: waves 0-3 -> E codes w*64, waves 4-7 -> X rows (w-4)*64
    const bool isE = w < 4;
    const int4* gbase = isE ? (e_t + cbase + w * 64 + lane)
                            : (x_t + row0 + (w - 4) * 64 + lane);
    const size_t gstride = isE ? KCODES : NROWS;

    v4f acc[8][4];
    #pragma unroll
    for (int mi = 0; mi < 8; ++mi) {
        float4 sd = *(const float4*)(esqh + cbase + wm * 128 + mi * 16 + quad * 4);
        v4f sv = (v4f){sd.x, sd.y, sd.z, sd.w};
        #pragma unroll
        for (int nj = 0; nj < 4; ++nj) acc[mi][nj] = sv;
    }

    // stage one k-chunk (sq = S*8+q) of slab S into buf S&1
    auto issue_q = [&](int S, int q) {
        int buf = S & 1;
        short* ldst = isE ? &EH[buf][q][(w & 3) * 64][0]
                          : &XH[buf][q][(w & 3) * 64][0];
        dma16(gbase + (size_t)(S * 8 + q) * gstride, ldst);
    };

    // prologue: stage slab 0 fully; wait first half (q0-3), q4-7 stay in flight
    #pragma unroll
    for (int q = 0; q < 8; ++q) issue_q(0, q);
    asm volatile("s_waitcnt vmcnt(4)" ::: "memory");
    __builtin_amdgcn_s_barrier();

    for (int S = 0; S < 8; ++S) {
        const int buf = S & 1;
        const bool pf = (S < 7);
        v8s bh[4], ah[4];

        // ---------- phase 1: ks=0 (q=quad), mi 0-3 ----------
        #pragma unroll
        for (int nj = 0; nj < 4; ++nj)
            bh[nj] = *(const v8s*)(&XH[buf][quad][wn * 64 + nj * 16 + l15][0]);
        #pragma unroll
        for (int mi = 0; mi < 4; ++mi)
            ah[mi] = *(const v8s*)(&EH[buf][quad][wm * 128 + mi * 16 + l15][0]);
        if (pf) { issue_q(S + 1, 0); issue_q(S + 1, 1); }
        __builtin_amdgcn_s_barrier();
        asm volatile("s_waitcnt lgkmcnt(0)" ::: "memory");
        __builtin_amdgcn_s_setprio(1);
        #pragma unroll
        for (int mi = 0; mi < 4; ++mi)
            #pragma unroll
            for (int nj = 0; nj < 4; ++nj)
                acc[mi][nj] = __builtin_amdgcn_mfma_f32_16x16x32_bf16(ah[mi], bh[nj], acc[mi][nj], 0, 0, 0);
        __builtin_amdgcn_s_setprio(0);
        __builtin_amdgcn_s_barrier();

        // ---------- phase 2: ks=0, mi 4-7 (reuse bh) ----------
        #pragma unroll
        for (int mi = 0; mi < 4; ++mi)
            ah[mi] = *(const v8s*)(&EH[buf][quad][wm * 128 + (4 + mi) * 16 + l15][0]);
        if (pf) { issue_q(S + 1, 2); issue_q(S + 1, 3); }
        __builtin_amdgcn_s_barrier();
        asm volatile("s_waitcnt lgkmcnt(0)" ::: "memory");
        __builtin_amdgcn_s_setprio(1);
        #pragma unroll
        for (int mi = 0; mi < 4; ++mi)
            #pragma unroll
            for (int nj = 0; nj < 4; ++nj)
                acc[4 + mi][nj] = __builtin_amdgcn_mfma_f32_16x16x32_bf16(ah[mi], bh[nj], acc[4 + mi][nj], 0, 0, 0);
        __builtin_amdgcn_s_setprio(0);
        // half-slab boundary: slab-S q4-7 must have landed before phase 3
        if (pf) asm volatile("s_waitcnt vmcnt(4)" ::: "memory");
        else    asm volatile("s_waitcnt vmcnt(0)" ::: "memory");
        __builtin_amdgcn_s_barrier();

        // ---------- phase 3: ks=1 (q=4+quad), mi 0-3 ----------
        #pragma unroll
        for (int nj = 0; nj < 4; ++nj)
            bh[nj] = *(const v8s*)(&XH[buf][4 + quad][wn * 64 + nj * 16 + l15][0]);
        #pragma unroll
        for (int mi = 0; mi < 4; ++mi)
            ah[mi] = *(const v8s*)(&EH[buf][4 + quad][wm * 128 + mi * 16 + l15][0]);
        if (pf) { issue_q(S + 1, 4); issue_q(S + 1, 5); }
        __builtin_amdgcn_s_barrier();
        asm volatile("s_waitcnt lgkmcnt(0)" ::: "memory");
        __builtin_amdgcn_s_setprio(1);
        #pragma unroll
        for (int mi = 0; mi < 4; ++mi)
            #pragma unroll
            for (int nj = 0; nj < 4; ++nj)
                acc[mi][nj] = __builtin_amdgcn_mfma_f32_16x16x32_bf16(ah[mi], bh[nj], acc[mi][nj], 0, 0, 0);
        __builtin_amdgcn_s_setprio(0);
        __builtin_amdgcn_s_barrier();

        // ---------- phase 4: ks=1, mi 4-7 (reuse bh) ----------
        #pragma unroll
        for (int mi = 0; mi < 4; ++mi)
            ah[mi] = *(const v8s*)(&EH[buf][4 + quad][wm * 128 + (4 + mi) * 16 + l15][0]);
        if (pf) { issue_q(S + 1, 6); issue_q(S + 1, 7); }
        __builtin_amdgcn_s_barrier();
        asm volatile("s_waitcnt lgkmcnt(0)" ::: "memory");
        __builtin_amdgcn_s_setprio(1);
        #pragma unroll
        for (int mi = 0; mi < 4; ++mi)
            #pragma unroll
            for (int nj = 0; nj < 4; ++nj)
                acc[4 + mi][nj] = __builtin_amdgcn_mfma_f32_16x16x32_bf16(ah[mi], bh[nj], acc[4 + mi][nj], 0, 0, 0);
        __builtin_amdgcn_s_setprio(0);
        // slab boundary: slab-(S+1) q0-3 must have landed before next phase 1
        if (pf) asm volatile("s_waitcnt vmcnt(4)" ::: "memory");
        __builtin_amdgcn_s_barrier();
    }

    // ---- epilogue (once): group-8 max -> top-2 of 4 -> quad merge ----------
    #pragma unroll
    for (int nj = 0; nj < 4; ++nj) {
        float b1 = NEG_INF, b2 = NEG_INF;
        int   i1 = 0, i2 = 0;
        #pragma unroll
        for (int g = 0; g < 4; ++g) {
            v4f s0 = acc[2 * g][nj], s1 = acc[2 * g + 1][nj];
            float m = fmaxf(fmaxf(fmaxf(s0[0], s0[1]), fmaxf(s0[2], s0[3])),
                            fmaxf(fmaxf(s1[0], s1[1]), fmaxf(s1[2], s1[3])));
            int gid = cbase + wm * 128 + g * 32 + quad * 4;  // codes gid+{0..3,16..19}
            if (m > b1)      { b2 = b1; i2 = i1; b1 = m; i1 = gid; }
            else if (m > b2) { b2 = m;  i2 = gid; }
        }
        #pragma unroll
        for (int o = 16; o <= 32; o <<= 1) {   // merge across the 4 quads
            float c1 = __shfl_xor(b1, o, 64);
            int   j1 = __shfl_xor(i1, o, 64);
            float c2 = __shfl_xor(b2, o, 64);
            int   j2 = __shfl_xor(i2, o, 64);
            if (c1 > b1) {
                b2 = fmaxf(b1, c2); i2 = (b1 >= c2) ? i1 : j2;
                b1 = c1; i1 = j1;
            } else {
                i2 = (b2 >= c1) ? i2 : j1;
                b2 = fmaxf(b2, c1);
            }
        }
        if (quad == 0) {
            int row = row0 + wn * 64 + nj * 16 + l15;
            size_t b = (size_t)row * CPR + (ct * 4 + wm * 2);
            cand_s[b]     = b1;  cand_i[b]     = i1;
            cand_s[b + 1] = b2;  cand_i[b + 1] = i2;
        }
    }
}

// --------- kernel 2: exact fp32 rescore of surviving groups + gather --------
__global__ __launch_bounds__(256) void rescore_kernel(
    const float* __restrict__ x, const float* __restrict__ embed,
    const float* __restrict__ e_sq, const float* __restrict__ f_sq,
    const float* __restrict__ cand_s, const int* __restrict__ cand_i,
    float* __restrict__ out)
{
    int row = blockIdx.x * 4 + (threadIdx.x >> 6);
    int lane = threadIdx.x & 63;
    size_t cb = (size_t)row * CPR;

    float cs0 = cand_s[cb + lane];
    float cs1 = cand_s[cb + 64 + lane];
    int   ci0 = cand_i[cb + lane];
    int   ci1 = cand_i[cb + 64 + lane];

    float m = fmaxf(cs0, cs1);
    #pragma unroll
    for (int o = 32; o >= 1; o >>= 1) m = fmaxf(m, __shfl_xor(m, o, 64));

    unsigned long long mask0 = __ballot(cs0 >= m - MARGIN);
    unsigned long long mask1 = __ballot(cs1 >= m - MARGIN);

    const float4* xsrc = (const float4*)(x + (size_t)row * DIM + lane * 8);
    float4 xa = xsrc[0], xb = xsrc[1];
    float fsq = f_sq[row];

    float bd = NEG_INF;
    int   bi = 0x7fffffff;

    #pragma unroll
    for (int s = 0; s < 2; ++s) {
        unsigned long long mask = s ? mask1 : mask0;
        while (mask) {
            int p = __ffsll(mask) - 1;
            mask &= mask - 1;
            int base = __shfl(s ? ci1 : ci0, p);
            #pragma unroll
            for (int e8 = 0; e8 < 8; ++e8) {
                int c = base + ((e8 >> 2) << 4) + (e8 & 3);  // {0..3, 16..19}
                const float4* er = (const float4*)(embed + (size_t)c * DIM + lane * 8);
                float4 ea = er[0], eb = er[1];
                float part = xa.x*ea.x + xa.y*ea.y + xa.z*ea.z + xa.w*ea.w
                           + xb.x*eb.x + xb.y*eb.y + xb.z*eb.z + xb.w*eb.w;
                #pragma unroll
                for (int o = 32; o >= 1; o >>= 1) part += __shfl_xor(part, o, 64);
                float d = -((fsq - 2.0f * part) + e_sq[c]);   // np rounding order
                if (d > bd || (d == bd && c < bi)) { bd = d; bi = c; }
            }
        }
    }

    const float4* er = (const float4*)(embed + (size_t)bi * DIM + lane * 8);
    float4 qa = er[0], qb = er[1];
    float4* dst = (float4*)(out + (size_t)row * DIM + lane * 8);
    dst[0] = qa; dst[1] = qb;
    if (lane == 0) out[(size_t)NROWS * DIM + row] = (float)bi;
}

extern "C" void kernel_launch(void* const* d_in, const int* in_sizes, int n_in,
                              void* d_out, int out_size, void* d_ws, size_t ws_size,
                              hipStream_t stream)
{
    const float* x     = (const float*)d_in[0];   // [16384, 512] fp32
    const float* embed = (const float*)d_in[1];   // [8192, 512] fp32
    float* out = (float*)d_out;

    // ws layout (~25 MB), all 16B-aligned
    float* e_sq   = (float*)d_ws;                               // 8192
    float* esqh   = e_sq + KCODES;                              // 8192 (-e_sq/2)
    float* f_sq   = esqh + KCODES;                              // 16384
    float* cand_s = f_sq + NROWS;                               // 16384*128
    int*   cand_i = (int*)(cand_s + (size_t)NROWS * CPR);       // 16384*128
    int4*  e_t    = (int4*)(cand_i + (size_t)NROWS * CPR);      // [64][8192] int4 = 8 MB

    // x_t lives in d_out scratch (16 MB of 33.6 MB); rescore overwrites later.
    int4* x_t = (int4*)d_out;

    (void)in_sizes; (void)n_in; (void)out_size; (void)ws_size;

    convert_kernel<<<(KCODES + NROWS) / 64, 256, 0, stream>>>(
        x, embed, e_t, x_t, e_sq, esqh, f_sq);
    screen_kernel<<<2048, 512, 0, stream>>>(
        e_t, x_t, esqh, cand_s, cand_i);
    rescore_kernel<<<NROWS / 4, 256, 0, stream>>>(
        x, embed, e_sq, f_sq, cand_s, cand_i, out);
}